// Round 13
// baseline (45.833 us; speedup 1.0000x reference)
//
#include <hip/hip_runtime.h>

// BertWordEmbedder: B=64, T=512, H=768, W=256, D=256
// PROJECT-FIRST (linearity: mean(h) @ W == mean(h @ W)), lowest-traffic order:
//   prep:     [0..191] proj_w -> wt [256][768] bf16 ; [192..255] bounds
//   gemm_tok: P[32768x256] = hs[32768x768] @ W.  R12-proven double-buffered
//             LDS loop; BM=64 BN=256 BK=64; A converted fp32->bf16 in staging;
//             hs STREAMED exactly once (100 MB); XOR chunk-swizzled LDS.
//   pool:     one wave per (b,w): mean of P rows (L2/L3-hot) + bias -> out.
// Empty words: zero P-sum -> out = bias (matches reference).
// ws: [0) wt 393216 | [393216) bounds 65792 | [524288) P 16777216

#define NB 64
#define NT 512
#define NH 768
#define NW 256
#define ND 256

typedef __attribute__((ext_vector_type(8))) short short8;
typedef __attribute__((ext_vector_type(4))) float f32x4;
typedef __attribute__((ext_vector_type(4))) float float4v;
typedef __attribute__((ext_vector_type(4))) unsigned int uint4v;
typedef __attribute__((ext_vector_type(4))) unsigned short ushort4v;

__device__ __forceinline__ unsigned short f2bf(float f) {
    union { float f; unsigned u; } v; v.f = f;
    unsigned r = v.u + 0x7fffu + ((v.u >> 16) & 1u);  // RNE
    return (unsigned short)(r >> 16);
}
// pack 2 fp32 -> 2 bf16 in one dword (R4-proven numerics)
__device__ __forceinline__ unsigned pk2(float lo, float hi) {
    union { float f; unsigned u; } a, b; a.f = lo; b.f = hi;
    return ((b.u + 0x8000u) & 0xffff0000u) | ((a.u + 0x8000u) >> 16);
}

// merged prep: wt transpose (192 blocks) + bounds (64 blocks)  [proven]
__global__ void prep(const float* __restrict__ w, const int* __restrict__ wid,
                     unsigned short* __restrict__ wt, int* __restrict__ bounds) {
    __shared__ float tile[32][33];
    __shared__ int s[NT];
    const int tid = threadIdx.x, n = blockIdx.x;
    if (n < 192) {
        int tx = tid & 31, ty = tid >> 5;
        int k0 = (n % 24) * 32, n0 = (n / 24) * 32;
        #pragma unroll
        for (int i = 0; i < 4; ++i)
            tile[ty + 8 * i][tx] = w[(size_t)(k0 + ty + 8 * i) * ND + n0 + tx];
        __syncthreads();
        #pragma unroll
        for (int i = 0; i < 4; ++i)
            wt[(size_t)(n0 + ty + 8 * i) * NH + k0 + tx] = f2bf(tile[tx][ty + 8 * i]);
    } else {
        int b = n - 192;
        s[tid]       = wid[b * NT + tid];
        s[tid + 256] = wid[b * NT + tid + 256];
        __syncthreads();
        for (int w2 = tid; w2 <= NW; w2 += 256) {
            int lo = 0, hi = NT;
            while (lo < hi) { int m = (lo + hi) >> 1; if (s[m] < w2) lo = m + 1; else hi = m; }
            bounds[b * (NW + 1) + w2] = lo;
        }
    }
}

// P[32768x256] = hs @ W.  512 blocks (BM=64), 512 thr = 8 waves (2m x 4n),
// wave = 32x64 out tile. Double-buffered LDS, 1 barrier/K-step (R12 loop),
// loads issued a full step early; A cvt fp32->bf16 during staging.
__global__ __launch_bounds__(512)
void gemm_tok(const float* __restrict__ hs, const unsigned short* __restrict__ wt,
              unsigned short* __restrict__ P) {
    __shared__ unsigned short Asm[2][64][64];    // 16 KB
    __shared__ unsigned short Bsm[2][256][64];   // 64 KB

    const int tid = threadIdx.x, wave = tid >> 6, lane = tid & 63;
    const int cl = lane & 15, kg = lane >> 4;
    const size_t r0 = (size_t)blockIdx.x * 64;
    const int wm0 = (wave >> 2) * 32, c0w = (wave & 3) * 64;

    // A staging: 8 thr/row, each 8 fp32 (chunk scA of 8); B: 2 thr/row, 4 chunks
    const int srA = tid >> 3, scA = tid & 7;
    const int srB = tid >> 1, scB = (tid & 1) * 4;
    const float* agp = hs + (r0 + srA) * NH + scA * 8;
    const unsigned short* bgp = wt + (size_t)srB * NH + scB * 8;
    const int pA = (scA ^ (srA & 7)) * 8;        // swizzled ushort offset

    float4v fa0[2], fa1[2];
    uint4v rb0[4], rb1[4];

#define GLOAD(fa, rb, ks) {                                                   \
        fa[0] = *(const float4v*)(agp + (ks) * 64);                           \
        fa[1] = *(const float4v*)(agp + (ks) * 64 + 4);                       \
        _Pragma("unroll")                                                     \
        for (int i = 0; i < 4; ++i)                                           \
            rb[i] = *(const uint4v*)(bgp + (ks) * 64 + i * 8);                \
    }
#define SWRITE(buf, fa, rb) {                                                 \
        uint4v pa;                                                            \
        pa[0] = pk2(fa[0][0], fa[0][1]); pa[1] = pk2(fa[0][2], fa[0][3]);     \
        pa[2] = pk2(fa[1][0], fa[1][1]); pa[3] = pk2(fa[1][2], fa[1][3]);     \
        *(uint4v*)&Asm[buf][srA][pA] = pa;                                    \
        _Pragma("unroll")                                                     \
        for (int i = 0; i < 4; ++i)                                           \
            *(uint4v*)&Bsm[buf][srB][((scB + i) ^ (srB & 7)) * 8] = rb[i];    \
    }

    f32x4 acc[2][4];
    #pragma unroll
    for (int mt = 0; mt < 2; ++mt)
        #pragma unroll
        for (int nt = 0; nt < 4; ++nt)
            #pragma unroll
            for (int r = 0; r < 4; ++r) acc[mt][nt][r] = 0.f;

    auto compute = [&](int buf) {
        short8 af[2][2], bf[4][2];
        #pragma unroll
        for (int mt = 0; mt < 2; ++mt)
            #pragma unroll
            for (int km = 0; km < 2; ++km) {
                int row = wm0 + mt * 16 + cl;
                af[mt][km] = *(const short8*)&Asm[buf][row][((km * 4 + kg) ^ (row & 7)) * 8];
            }
        #pragma unroll
        for (int nt = 0; nt < 4; ++nt)
            #pragma unroll
            for (int km = 0; km < 2; ++km) {
                int row = c0w + nt * 16 + cl;
                bf[nt][km] = *(const short8*)&Bsm[buf][row][((km * 4 + kg) ^ (row & 7)) * 8];
            }
        #pragma unroll
        for (int mt = 0; mt < 2; ++mt)
            #pragma unroll
            for (int nt = 0; nt < 4; ++nt)
                #pragma unroll
                for (int km = 0; km < 2; ++km)
                    acc[mt][nt] = __builtin_amdgcn_mfma_f32_16x16x32_bf16(af[mt][km], bf[nt][km], acc[mt][nt], 0, 0, 0);
    };

    // R12-proven prologue + double-buffer loop (12 K-steps, 1 barrier each)
    GLOAD(fa0, rb0, 0);
    SWRITE(0, fa0, rb0);
    GLOAD(fa1, rb1, 1);
    __syncthreads();

    #pragma unroll 1
    for (int ks = 0; ks < 12; ks += 2) {
        if (ks + 2 < 12) GLOAD(fa0, rb0, ks + 2);
        SWRITE(1, fa1, rb1);
        compute(0);
        __syncthreads();
        if (ks + 3 < 12) GLOAD(fa1, rb1, ks + 3);
        if (ks + 2 < 12) SWRITE(0, fa0, rb0);
        compute(1);
        __syncthreads();
    }
#undef GLOAD
#undef SWRITE

    // C/D layout: col=lane&15, row=(lane>>4)*4+r  [proven R1-R12]
    #pragma unroll
    for (int mt = 0; mt < 2; ++mt)
        #pragma unroll
        for (int nt = 0; nt < 4; ++nt)
            #pragma unroll
            for (int r = 0; r < 4; ++r) {
                size_t row = r0 + wm0 + mt * 16 + kg * 4 + r;
                P[row * ND + c0w + nt * 16 + cl] = f2bf(acc[mt][nt][r]);
            }
}

// one wave per (b,w): mean of P token-rows (L2/L3-hot) + bias -> out  [R4-proven]
__global__ __launch_bounds__(256)
void pool(const unsigned short* __restrict__ P, const int* __restrict__ bounds,
          const float* __restrict__ bias, float* __restrict__ out) {
    const int wave = threadIdx.x >> 6, lane = threadIdx.x & 63;
    const int idx = blockIdx.x * 4 + wave;           // 0..16383
    const int b = idx >> 8, w = idx & 255;
    int s = __builtin_amdgcn_readfirstlane(bounds[b * (NW + 1) + w]);
    int e = __builtin_amdgcn_readfirstlane(bounds[b * (NW + 1) + w + 1]);

    const unsigned short* base = P + (size_t)b * NT * ND + lane * 4;
    float a0 = 0.f, a1 = 0.f, a2 = 0.f, a3 = 0.f;

    int t = s;
    for (; t + 4 <= e; t += 4) {                     // 4 rows in flight
        ushort4v v0 = *(const ushort4v*)(base + (size_t)(t    ) * ND);
        ushort4v v1 = *(const ushort4v*)(base + (size_t)(t + 1) * ND);
        ushort4v v2 = *(const ushort4v*)(base + (size_t)(t + 2) * ND);
        ushort4v v3 = *(const ushort4v*)(base + (size_t)(t + 3) * ND);
        union { unsigned u; float f; } c;
        #define ADD(v) { c.u = (unsigned)(v)[0] << 16; a0 += c.f; \
                         c.u = (unsigned)(v)[1] << 16; a1 += c.f; \
                         c.u = (unsigned)(v)[2] << 16; a2 += c.f; \
                         c.u = (unsigned)(v)[3] << 16; a3 += c.f; }
        ADD(v0) ADD(v1) ADD(v2) ADD(v3)
    }
    for (; t < e; ++t) {
        ushort4v v = *(const ushort4v*)(base + (size_t)t * ND);
        union { unsigned u; float f; } c;
        ADD(v)
        #undef ADD
    }

    int cnt = e - s; if (cnt < 1) cnt = 1;
    float sc = 1.0f / (float)cnt;
    float4v bv = *(const float4v*)(bias + lane * 4);
    float4v o;
    o[0] = a0 * sc + bv[0]; o[1] = a1 * sc + bv[1];
    o[2] = a2 * sc + bv[2]; o[3] = a3 * sc + bv[3];
    *(float4v*)(out + ((size_t)b * NW + w) * ND + lane * 4) = o;
}

extern "C" void kernel_launch(void* const* d_in, const int* in_sizes, int n_in,
                              void* d_out, int out_size, void* d_ws, size_t ws_size,
                              hipStream_t stream) {
    const float* hs  = (const float*)d_in[0];
    const int*   wid = (const int*)d_in[1];
    const float* pw  = (const float*)d_in[2];
    const float* pb  = (const float*)d_in[3];
    float* out = (float*)d_out;

    unsigned short* wt = (unsigned short*)d_ws;                      // 393216 B
    int* bounds        = (int*)((char*)d_ws + 393216);               // 65792 B
    unsigned short* P  = (unsigned short*)((char*)d_ws + 524288);    // 16777216 B

    prep<<<256, 256, 0, stream>>>(pw, wid, wt, bounds);
    gemm_tok<<<(NB * NT) / 64, 512, 0, stream>>>(hs, wt, P);
    pool<<<(NB * NW) / 4, 256, 0, stream>>>(P, bounds, pb, out);
}

// Round 14
// 43.020 us; speedup vs baseline: 1.0654x; 1.0654x over previous
//
#include <hip/hip_runtime.h>

// BertWordEmbedder: B=64, T=512, H=768, W=256, D=256
// TWO-KERNEL pipeline (was 3 + prep):
//   K1 pool_comb: blocks 0..2047  = pool word-pairs for (b, word-group of 8):
//                   stage wid[b,:] in LDS, waves binary-search their OWN bounds
//                   (no prep dependency), then R8-proven pair-pooling -> we bf16.
//                 blocks 2048..2239 = proj_w -> wt [256][768] bf16 transpose
//                   (independent inputs/outputs -> same launch, no ordering).
//   K2 gemm_lds:  R12-proven 64x64x64 double-buffered LDS MFMA GEMM -> out.
// Empty words: zero we row -> out = bias (matches reference).
// ws: [0) wt 393216 | [393216) (unused) | [524288) we 25165824

#define NB 64
#define NT 512
#define NH 768
#define NW 256
#define ND 256

typedef __attribute__((ext_vector_type(8))) short short8;
typedef __attribute__((ext_vector_type(4))) float f32x4;
typedef __attribute__((ext_vector_type(4))) float float4v;
typedef __attribute__((ext_vector_type(4))) unsigned int uint4v;
typedef __attribute__((ext_vector_type(4))) unsigned short ushort4v;

__device__ __forceinline__ unsigned short f2bf(float f) {
    union { float f; unsigned u; } v; v.f = f;
    unsigned r = v.u + 0x7fffu + ((v.u >> 16) & 1u);  // RNE
    return (unsigned short)(r >> 16);
}

union PoolSmem {
    int wid[NT];          // pool path: 2 KB
    float tile[32][33];   // transpose path: 4.2 KB
};

// K1: pool (2048 blocks) + wt transpose (192 blocks), one launch
__global__ __launch_bounds__(256, 8)
void pool_comb(const float* __restrict__ hs, const int* __restrict__ wid,
               const float* __restrict__ pw,
               unsigned short* __restrict__ we, unsigned short* __restrict__ wt) {
    __shared__ PoolSmem sm;
    const int tid = threadIdx.x, bid = blockIdx.x;

    if (bid >= 2048) {                 // ---- wt transpose (R7-proven pattern) ----
        const int n2 = bid - 2048;     // 0..191
        int tx = tid & 31, ty = tid >> 5;
        int k0 = (n2 % 24) * 32, n0 = (n2 / 24) * 32;
        #pragma unroll
        for (int i = 0; i < 4; ++i)
            sm.tile[ty + 8 * i][tx] = pw[(size_t)(k0 + ty + 8 * i) * ND + n0 + tx];
        __syncthreads();
        #pragma unroll
        for (int i = 0; i < 4; ++i)
            wt[(size_t)(n0 + ty + 8 * i) * NH + k0 + tx] = f2bf(sm.tile[tx][ty + 8 * i]);
        return;
    }

    // ---- pool: block = (b, group of 8 words); wave = one word pair ----
    const int wave = tid >> 6, lane = tid & 63;
    const int b = bid >> 5, g = bid & 31;

    sm.wid[tid]       = wid[b * NT + tid];
    sm.wid[tid + 256] = wid[b * NT + tid + 256];
    __syncthreads();

    const int wp = g * 8 + 2 * wave;   // first word of this wave's pair
    int bnd[3];
    #pragma unroll
    for (int q = 0; q < 3; ++q) {      // lower_bound(wp+q), uniform across lanes
        int v = wp + q, lo = 0, hi = NT;
        while (lo < hi) { int mid = (lo + hi) >> 1; if (sm.wid[mid] < v) lo = mid + 1; else hi = mid; }
        bnd[q] = lo;
    }
    const int s = bnd[0], m = bnd[1], e = bnd[2];

    const float* base = hs + (size_t)b * NT * NH + lane * 4;
    float4v a0c0 = {0,0,0,0}, a0c1 = {0,0,0,0}, a0c2 = {0,0,0,0};
    float4v a1c0 = {0,0,0,0}, a1c1 = {0,0,0,0}, a1c2 = {0,0,0,0};

#define ROUTE(t, v0, v1, v2) {                                                \
        if ((t) < m) {                                                        \
            _Pragma("unroll") for (int q = 0; q < 4; ++q) {                   \
                a0c0[q] += (v0)[q]; a0c1[q] += (v1)[q]; a0c2[q] += (v2)[q]; } \
        } else {                                                              \
            _Pragma("unroll") for (int q = 0; q < 4; ++q) {                   \
                a1c0[q] += (v0)[q]; a1c1[q] += (v1)[q]; a1c2[q] += (v2)[q]; } \
        }                                                                     \
    }
    int t = s;
    for (; t + 2 <= e; t += 2) {                    // 6 loads in flight
        float4v v[2][3];
        #pragma unroll
        for (int u = 0; u < 2; ++u) {
            const float* p = base + (size_t)(t + u) * NH;
            v[u][0] = *(const float4v*)(p);
            v[u][1] = *(const float4v*)(p + 256);
            v[u][2] = *(const float4v*)(p + 512);
        }
        #pragma unroll
        for (int u = 0; u < 2; ++u) ROUTE(t + u, v[u][0], v[u][1], v[u][2]);
    }
    if (t < e) {
        const float* p = base + (size_t)t * NH;
        float4v v0 = *(const float4v*)(p);
        float4v v1 = *(const float4v*)(p + 256);
        float4v v2 = *(const float4v*)(p + 512);
        ROUTE(t, v0, v1, v2);
    }
#undef ROUTE

    int c0 = m - s; if (c0 < 1) c0 = 1;
    int c1 = e - m; if (c1 < 1) c1 = 1;
    const float s0 = 1.0f / (float)c0, s1 = 1.0f / (float)c1;

    const int pairIdx = b * 128 + g * 4 + wave;     // 0..8191
    unsigned short* d0 = we + (size_t)(2 * pairIdx) * NH + lane * 4;
    unsigned short* d1 = d0 + NH;
    ushort4v u;
    #pragma unroll
    for (int q = 0; q < 4; ++q) u[q] = f2bf(a0c0[q] * s0);
    *(ushort4v*)(d0) = u;
    #pragma unroll
    for (int q = 0; q < 4; ++q) u[q] = f2bf(a0c1[q] * s0);
    *(ushort4v*)(d0 + 256) = u;
    #pragma unroll
    for (int q = 0; q < 4; ++q) u[q] = f2bf(a0c2[q] * s0);
    *(ushort4v*)(d0 + 512) = u;
    #pragma unroll
    for (int q = 0; q < 4; ++q) u[q] = f2bf(a1c0[q] * s1);
    *(ushort4v*)(d1) = u;
    #pragma unroll
    for (int q = 0; q < 4; ++q) u[q] = f2bf(a1c1[q] * s1);
    *(ushort4v*)(d1 + 256) = u;
    #pragma unroll
    for (int q = 0; q < 4; ++q) u[q] = f2bf(a1c2[q] * s1);
    *(ushort4v*)(d1 + 512) = u;
}

// K2: out[16384x256] = we @ wt^T + bias.  R12-proven (CONTROL, unchanged):
// BM=64 BN=64 BK=64, 1024 blocks (4/CU), double-buffered, 1 barrier/K-step,
// XOR chunk-swizzle, XCD-chunked block swizzle.
__global__ __launch_bounds__(256, 4)
void gemm_lds(const unsigned short* __restrict__ we, const unsigned short* __restrict__ wt,
              const float* __restrict__ bias, float* __restrict__ out) {
    __shared__ unsigned short Abuf[2][64][64];
    __shared__ unsigned short Bbuf[2][64][64];

    const int tid = threadIdx.x, wave = tid >> 6, lane = tid & 63;
    const int cl = lane & 15, kg = lane >> 4;
    const int bid = blockIdx.x;                       // 0..1023
    const int swz = (bid & 7) * 128 + (bid >> 3);     // bijective (1024 % 8 == 0)
    const size_t r0 = (size_t)(swz >> 2) * 64;
    const int c0 = (swz & 3) * 64;
    const int wm0 = (wave >> 1) * 32, wn0 = (wave & 1) * 32;

    const int srow = tid >> 2, sc = tid & 3;
    const int p0 = (sc ^ (srow & 7)) * 8;
    const int p1 = ((sc + 4) ^ (srow & 7)) * 8;
    const unsigned short* agp = we + (r0 + srow) * NH + sc * 8;
    const unsigned short* bgp = wt + (size_t)(c0 + srow) * NH + sc * 8;

    uint4v ra0[2], rb0[2], ra1[2], rb1[2];

#define GLOAD(ra, rb, ks) {                                                   \
        ra[0] = *(const uint4v*)(agp + (ks) * 64);                            \
        ra[1] = *(const uint4v*)(agp + (ks) * 64 + 32);                       \
        rb[0] = *(const uint4v*)(bgp + (ks) * 64);                            \
        rb[1] = *(const uint4v*)(bgp + (ks) * 64 + 32);                       \
    }
#define SWRITE(buf, ra, rb) {                                                 \
        *(uint4v*)&Abuf[buf][srow][p0] = ra[0];                               \
        *(uint4v*)&Abuf[buf][srow][p1] = ra[1];                               \
        *(uint4v*)&Bbuf[buf][srow][p0] = rb[0];                               \
        *(uint4v*)&Bbuf[buf][srow][p1] = rb[1];                               \
    }

    f32x4 acc[2][2];
    #pragma unroll
    for (int mt = 0; mt < 2; ++mt)
        #pragma unroll
        for (int nt = 0; nt < 2; ++nt)
            #pragma unroll
            for (int r = 0; r < 4; ++r) acc[mt][nt][r] = 0.f;

    auto compute = [&](int buf) {
        short8 af[2][2], bf[2][2];
        #pragma unroll
        for (int mt = 0; mt < 2; ++mt)
            #pragma unroll
            for (int km = 0; km < 2; ++km) {
                int row = wm0 + mt * 16 + cl;
                af[mt][km] = *(const short8*)&Abuf[buf][row][((km * 4 + kg) ^ (row & 7)) * 8];
            }
        #pragma unroll
        for (int nt = 0; nt < 2; ++nt)
            #pragma unroll
            for (int km = 0; km < 2; ++km) {
                int row = wn0 + nt * 16 + cl;
                bf[nt][km] = *(const short8*)&Bbuf[buf][row][((km * 4 + kg) ^ (row & 7)) * 8];
            }
        #pragma unroll
        for (int mt = 0; mt < 2; ++mt)
            #pragma unroll
            for (int nt = 0; nt < 2; ++nt)
                #pragma unroll
                for (int km = 0; km < 2; ++km)
                    acc[mt][nt] = __builtin_amdgcn_mfma_f32_16x16x32_bf16(af[mt][km], bf[nt][km], acc[mt][nt], 0, 0, 0);
    };

    GLOAD(ra0, rb0, 0);
    SWRITE(0, ra0, rb0);
    GLOAD(ra1, rb1, 1);
    __syncthreads();

    #pragma unroll 1
    for (int ks = 0; ks < 12; ks += 2) {
        if (ks + 2 < 12) GLOAD(ra0, rb0, ks + 2);
        SWRITE(1, ra1, rb1);
        compute(0);
        __syncthreads();
        if (ks + 3 < 12) GLOAD(ra1, rb1, ks + 3);
        if (ks + 2 < 12) SWRITE(0, ra0, rb0);
        compute(1);
        __syncthreads();
    }
#undef GLOAD
#undef SWRITE

    float bv[2];
    bv[0] = bias[c0 + wn0 + cl];
    bv[1] = bias[c0 + wn0 + 16 + cl];

    // C/D layout: col=lane&15, row=(lane>>4)*4+r  [proven R1-R13]
    #pragma unroll
    for (int mt = 0; mt < 2; ++mt)
        #pragma unroll
        for (int nt = 0; nt < 2; ++nt)
            #pragma unroll
            for (int r = 0; r < 4; ++r)
                out[(r0 + wm0 + mt * 16 + kg * 4 + r) * ND + c0 + wn0 + nt * 16 + cl]
                    = acc[mt][nt][r] + bv[nt];
}

extern "C" void kernel_launch(void* const* d_in, const int* in_sizes, int n_in,
                              void* d_out, int out_size, void* d_ws, size_t ws_size,
                              hipStream_t stream) {
    const float* hs  = (const float*)d_in[0];
    const int*   wid = (const int*)d_in[1];
    const float* pw  = (const float*)d_in[2];
    const float* pb  = (const float*)d_in[3];
    float* out = (float*)d_out;

    unsigned short* wt = (unsigned short*)d_ws;                      // 393216 B
    unsigned short* we = (unsigned short*)((char*)d_ws + 524288);    // 25165824 B

    pool_comb<<<2048 + 192, 256, 0, stream>>>(hs, wid, pw, we, wt);
    gemm_lds<<<NB * NW / 64 * (ND / 64), 256, 0, stream>>>(we, wt, pb, out);
}

// Round 15
// 36.049 us; speedup vs baseline: 1.2714x; 1.1934x over previous
//
#include <hip/hip_runtime.h>

// BertWordEmbedder: B=64, T=512, H=768, W=256, D=256
// TWO kernels, no intermediate we:
//   prep_wt2: proj_w [768][256] f32 -> wt2 TILED bf16 [ct=16][kc=96][16col][8k]
//             (B-fragment loads become single 1KB coalesced L2 reads)
//   fused:    block = (b, 32-word group) x full D. Phase A: R8-proven
//             contiguous-stream pair pooling -> LDS A[32][776] bf16 (ONCE).
//             Phase B: 24-step K-loop, A from LDS, B direct from wt2 (L2),
//             ZERO barriers in-loop, ping-pong reg prefetch. + bias -> out.
// Empty words: zero A row -> out = bias (matches reference).
// ws: [0) wt2 393216 B

#define NB 64
#define NT 512
#define NH 768
#define NW 256
#define ND 256
#define PAD 8
#define ROWE (NH + PAD)   // 776

typedef __attribute__((ext_vector_type(8))) short short8;
typedef __attribute__((ext_vector_type(4))) float f32x4;
typedef __attribute__((ext_vector_type(4))) float float4v;
typedef __attribute__((ext_vector_type(4))) unsigned short ushort4v;

__device__ __forceinline__ unsigned short f2bf(float f) {
    union { float f; unsigned u; } v; v.f = f;
    unsigned r = v.u + 0x7fffu + ((v.u >> 16) & 1u);  // RNE
    return (unsigned short)(r >> 16);
}

// proj_w -> tiled wt2: element (k, col) at [((col>>4)*96 + (k>>3))*16 + (col&15)]*8 + (k&7)
__global__ void prep_wt2(const float* __restrict__ w, unsigned short* __restrict__ wt2) {
    __shared__ float tile[32][33];   // [kk][cc]
    const int tid = threadIdx.x, n = blockIdx.x;
    const int tx = tid & 31, ty = tid >> 5;
    const int k0 = (n % 24) * 32, n0 = (n / 24) * 32;
    #pragma unroll
    for (int i = 0; i < 4; ++i)
        tile[ty + 8 * i][tx] = w[(size_t)(k0 + ty + 8 * i) * ND + n0 + tx];
    __syncthreads();
    if (tid < 128) {
        const int cc = tid & 31, q = tid >> 5;        // q = 0..3 (8-k chunk)
        const int col = n0 + cc;
        ushort4v u0, u1;
        #pragma unroll
        for (int j = 0; j < 4; ++j) u0[j] = f2bf(tile[q * 8 + j][cc]);
        #pragma unroll
        for (int j = 0; j < 4; ++j) u1[j] = f2bf(tile[q * 8 + 4 + j][cc]);
        size_t off = (((size_t)(col >> 4) * 96 + (k0 >> 3) + q) * 16 + (col & 15)) * 8;
        *(ushort4v*)&wt2[off]     = u0;
        *(ushort4v*)&wt2[off + 4] = u1;
    }
}

// fused pool+GEMM. 512 blocks = (b, 32-word group), 256 thr = 4 waves.
__global__ __launch_bounds__(256, 3)
void fused(const float* __restrict__ hs, const int* __restrict__ wid,
           const unsigned short* __restrict__ wt2, const float* __restrict__ pb,
           float* __restrict__ out) {
    __shared__ unsigned short A[32][ROWE];   // 49664 B
    __shared__ int swid[NT];
    __shared__ int sb[33];

    const int tid = threadIdx.x, bid = blockIdx.x;
    const int wave = tid >> 6, lane = tid & 63;
    const int b = bid >> 3, w0 = (bid & 7) * 32;

    // stage word ids; parallel bounds (33 searches, one per thread)
    swid[tid]       = wid[b * NT + tid];
    swid[tid + 256] = wid[b * NT + tid + 256];
    __syncthreads();
    if (tid <= 32) {
        int v = w0 + tid, lo = 0, hi = NT;
        while (lo < hi) { int mid = (lo + hi) >> 1; if (swid[mid] < v) lo = mid + 1; else hi = mid; }
        sb[tid] = lo;
    }
    __syncthreads();

    // ---- Phase A: pool 16 word-pairs (R8-proven streaming), 4 pairs/wave ----
    const float* base = hs + (size_t)b * NT * NH + lane * 4;
    #pragma unroll 1
    for (int pp = 0; pp < 4; ++pp) {
        const int p = wave * 4 + pp;                 // pair 0..15, rows 2p,2p+1
        const int s = sb[2 * p], m = sb[2 * p + 1], e = sb[2 * p + 2];

        float4v a0c0 = {0,0,0,0}, a0c1 = {0,0,0,0}, a0c2 = {0,0,0,0};
        float4v a1c0 = {0,0,0,0}, a1c1 = {0,0,0,0}, a1c2 = {0,0,0,0};
#define ROUTE(t, v0, v1, v2) {                                                \
        if ((t) < m) {                                                        \
            _Pragma("unroll") for (int q = 0; q < 4; ++q) {                   \
                a0c0[q] += (v0)[q]; a0c1[q] += (v1)[q]; a0c2[q] += (v2)[q]; } \
        } else {                                                              \
            _Pragma("unroll") for (int q = 0; q < 4; ++q) {                   \
                a1c0[q] += (v0)[q]; a1c1[q] += (v1)[q]; a1c2[q] += (v2)[q]; } \
        }                                                                     \
    }
        int t = s;
        for (; t + 2 <= e; t += 2) {                 // 6 loads in flight
            float4v v[2][3];
            #pragma unroll
            for (int u = 0; u < 2; ++u) {
                const float* p2 = base + (size_t)(t + u) * NH;
                v[u][0] = *(const float4v*)(p2);
                v[u][1] = *(const float4v*)(p2 + 256);
                v[u][2] = *(const float4v*)(p2 + 512);
            }
            #pragma unroll
            for (int u = 0; u < 2; ++u) ROUTE(t + u, v[u][0], v[u][1], v[u][2]);
        }
        if (t < e) {
            const float* p2 = base + (size_t)t * NH;
            float4v v0 = *(const float4v*)(p2);
            float4v v1 = *(const float4v*)(p2 + 256);
            float4v v2 = *(const float4v*)(p2 + 512);
            ROUTE(t, v0, v1, v2);
        }
#undef ROUTE
        int c0n = m - s; if (c0n < 1) c0n = 1;
        int c1n = e - m; if (c1n < 1) c1n = 1;
        const float s0 = 1.0f / (float)c0n, s1 = 1.0f / (float)c1n;
        ushort4v u;
        #pragma unroll
        for (int q = 0; q < 4; ++q) u[q] = f2bf(a0c0[q] * s0);
        *(ushort4v*)&A[2 * p][lane * 4] = u;
        #pragma unroll
        for (int q = 0; q < 4; ++q) u[q] = f2bf(a0c1[q] * s0);
        *(ushort4v*)&A[2 * p][256 + lane * 4] = u;
        #pragma unroll
        for (int q = 0; q < 4; ++q) u[q] = f2bf(a0c2[q] * s0);
        *(ushort4v*)&A[2 * p][512 + lane * 4] = u;
        #pragma unroll
        for (int q = 0; q < 4; ++q) u[q] = f2bf(a1c0[q] * s1);
        *(ushort4v*)&A[2 * p + 1][lane * 4] = u;
        #pragma unroll
        for (int q = 0; q < 4; ++q) u[q] = f2bf(a1c1[q] * s1);
        *(ushort4v*)&A[2 * p + 1][256 + lane * 4] = u;
        #pragma unroll
        for (int q = 0; q < 4; ++q) u[q] = f2bf(a1c2[q] * s1);
        *(ushort4v*)&A[2 * p + 1][512 + lane * 4] = u;
    }
    __syncthreads();

    // ---- Phase B: GEMM [32x768]x[768x256], zero in-loop barriers ----
    const int cl = lane & 15, kg = lane >> 4;
    const int c0w = wave * 64;
    // B chunk [ct][kc] = 128 ushorts; lane slot kg*128? no: within chunk lane
    // reads (cl)*8; kc = ks*4 + kg. bgp points at (ct_base, kc=kg, cl):
    const unsigned short* bgp = wt2 + (size_t)(wave * 4) * 12288 + kg * 128 + cl * 8;

    short8 a0[2], a1[2], b0[4], b1[4];
    f32x4 acc[2][4];
    #pragma unroll
    for (int mt = 0; mt < 2; ++mt)
        #pragma unroll
        for (int nt = 0; nt < 4; ++nt)
            #pragma unroll
            for (int r = 0; r < 4; ++r) acc[mt][nt][r] = 0.f;

#define LDA(d, ks) { d[0] = *(const short8*)&A[cl][(ks) * 32 + kg * 8];       \
                     d[1] = *(const short8*)&A[16 + cl][(ks) * 32 + kg * 8]; }
#define LDB(d, ks) { _Pragma("unroll")                                        \
                     for (int nt = 0; nt < 4; ++nt)                           \
                         d[nt] = *(const short8*)(bgp + nt * 12288 + (ks) * 512); }
#define MM(a, bb) { _Pragma("unroll")                                         \
                    for (int mt = 0; mt < 2; ++mt)                            \
                        _Pragma("unroll")                                     \
                        for (int nt = 0; nt < 4; ++nt)                        \
                            acc[mt][nt] = __builtin_amdgcn_mfma_f32_16x16x32_bf16(a[mt], bb[nt], acc[mt][nt], 0, 0, 0); }

    LDA(a0, 0); LDB(b0, 0);
    #pragma unroll 1
    for (int i = 0; i < 12; ++i) {
        const int ks = 2 * i;
        LDA(a1, ks + 1); LDB(b1, ks + 1);
        MM(a0, b0);
        if (i < 11) { LDA(a0, ks + 2); LDB(b0, ks + 2); }
        MM(a1, b1);
    }
#undef LDA
#undef LDB
#undef MM

    float bv[4];
    #pragma unroll
    for (int nt = 0; nt < 4; ++nt) bv[nt] = pb[c0w + nt * 16 + cl];

    // C/D layout: col=lane&15, row=(lane>>4)*4+r  [proven R1-R14]
    #pragma unroll
    for (int mt = 0; mt < 2; ++mt)
        #pragma unroll
        for (int nt = 0; nt < 4; ++nt)
            #pragma unroll
            for (int r = 0; r < 4; ++r)
                out[((size_t)b * NW + w0 + mt * 16 + kg * 4 + r) * ND + c0w + nt * 16 + cl]
                    = acc[mt][nt][r] + bv[nt];
}

extern "C" void kernel_launch(void* const* d_in, const int* in_sizes, int n_in,
                              void* d_out, int out_size, void* d_ws, size_t ws_size,
                              hipStream_t stream) {
    const float* hs  = (const float*)d_in[0];
    const int*   wid = (const int*)d_in[1];
    const float* pw  = (const float*)d_in[2];
    const float* pb  = (const float*)d_in[3];
    float* out = (float*)d_out;

    unsigned short* wt2 = (unsigned short*)d_ws;     // 393216 B

    prep_wt2<<<192, 256, 0, stream>>>(pw, wt2);
    fused<<<NB * (NW / 32), 256, 0, stream>>>(hs, wid, wt2, pb, out);
}